// Round 3
// baseline (322.985 us; speedup 1.0000x reference)
//
#include <hip/hip_runtime.h>
#include <hip/hip_bf16.h>
#include <stdint.h>

// Self-attention: out = softmax((xWq+bq)(xWk+bk)^T / 32) (xWv+bv) Wo + bo
// B=4, C=2048, D_IN=D_H=D_OUT=1024. fp32 in/out; bf16 MFMA internally.

typedef unsigned short u16;
typedef __attribute__((ext_vector_type(8))) short bf16x8;   // 8 bf16 = 4 VGPR
typedef __attribute__((ext_vector_type(4))) float f32x4;    // MFMA 16x16 acc

#define BATCH 4
#define CSEQ  2048
#define DIM   1024

__device__ __forceinline__ u16 f2bf(float f) {
  union { float f; uint32_t u; } v; v.f = f;
  uint32_t r = (v.u + 0x7fffu + ((v.u >> 16) & 1u)) >> 16;  // RNE
  return (u16)r;
}

__device__ __forceinline__ void gload_lds16(const void* g, void* lds) {
  // async global->LDS, 16B per lane; LDS dest = wave-uniform base + lane*16
  __builtin_amdgcn_global_load_lds(
      (const __attribute__((address_space(1))) unsigned int*)g,
      (__attribute__((address_space(3))) unsigned int*)lds, 16, 0, 0);
}

// ---------------------------------------------------------------------------
// cast fp32 -> bf16, vectorized
__global__ __launch_bounds__(256) void cast_f32_bf16(
    const float4* __restrict__ in, ushort4* __restrict__ out, int n4) {
  int i = blockIdx.x * 256 + threadIdx.x;
  if (i < n4) {
    float4 v = in[i];
    ushort4 o;
    o.x = f2bf(v.x); o.y = f2bf(v.y); o.z = f2bf(v.z); o.w = f2bf(v.w);
    out[i] = o;
  }
}

// transpose + cast fp32 W[rows][cols] -> bf16 Wt[cols][rows]
__global__ __launch_bounds__(256) void transpose_cast_w(
    const float* __restrict__ W, u16* __restrict__ Wt, int rows, int cols) {
  __shared__ float t[32][33];
  int bx = blockIdx.x * 32;  // col base
  int by = blockIdx.y * 32;  // row base
  int tx = threadIdx.x, ty = threadIdx.y;  // 32 x 8
#pragma unroll
  for (int i = 0; i < 4; ++i)
    t[ty + i * 8][tx] = W[(size_t)(by + ty + i * 8) * cols + bx + tx];
  __syncthreads();
#pragma unroll
  for (int i = 0; i < 4; ++i)
    Wt[(size_t)(bx + ty + i * 8) * rows + by + tx] = f2bf(t[tx][ty + i * 8]);
}

// transpose bf16 V[z][rows][cols] -> Vt[z][cols][rows]
__global__ __launch_bounds__(256) void transpose_bf16(
    const u16* __restrict__ V, u16* __restrict__ Vt, int rows, int cols) {
  __shared__ u16 t[32][34];
  size_t ib = (size_t)blockIdx.z * rows * cols;
  int bx = blockIdx.x * 32;  // col base
  int by = blockIdx.y * 32;  // row base
  int tx = threadIdx.x, ty = threadIdx.y;
#pragma unroll
  for (int i = 0; i < 4; ++i)
    t[ty + i * 8][tx] = V[ib + (size_t)(by + ty + i * 8) * cols + bx + tx];
  __syncthreads();
#pragma unroll
  for (int i = 0; i < 4; ++i)
    Vt[ib + (size_t)(bx + ty + i * 8) * rows + by + tx] = t[tx][ty + i * 8];
}

// ---------------------------------------------------------------------------
// Generic bf16 GEMM: C[M][N] (+bias) (*scale) = A[M][K] * Bt[N][K]^T
// 128x128 tile, BK=64, 256 threads (4 waves, 2x2), 4x4 16x16x32 frags/wave.
// LDS double-buffered, global_load_lds staging, XOR slot swizzle (T2).
template <bool OUT_BF16, bool HAS_BIAS>
__global__ __launch_bounds__(256, 2) void gemm_bt(
    const u16* __restrict__ A, const u16* __restrict__ Bt, void* __restrict__ C,
    const float* __restrict__ bias, int M, int N, int K, int lda, int ldb,
    int ldc, size_t sA, size_t sB, size_t sC, float scale) {
  __shared__ __align__(16) u16 As[2][128 * 64];
  __shared__ __align__(16) u16 Bs[2][128 * 64];

  const int tid = threadIdx.x;
  const int lane = tid & 63;
  const int w = tid >> 6;
  const int wm = w >> 1, wn = w & 1;
  const int bz = blockIdx.z;
  const int m0 = blockIdx.y * 128;
  const int n0 = blockIdx.x * 128;

  A += (size_t)bz * sA;
  Bt += (size_t)bz * sB;

  f32x4 acc[4][4] = {};

  // stage one 128x64 A-tile + B-tile into LDS buffer `buf` at k-offset k0.
  // LDS physical layout: row-major [128][64], 8 slots of 16B per row,
  // slot swizzle: phys = logical ^ (row&7). global_load_lds writes linearly,
  // so the *source* address is inverse-swizzled (rule #21: both sides).
  auto stage = [&](int buf, int k0) {
#pragma unroll
    for (int r = 0; r < 4; ++r) {
      int flat = r * 256 + tid;           // 16B unit index
      int row = flat >> 3;                // 8 x 16B per row
      int s = (flat & 7) ^ (row & 7);     // logical slot this lane must fetch
      const u16* ga = A + (size_t)(m0 + row) * lda + (k0 + s * 8);
      const u16* gb = Bt + (size_t)(n0 + row) * ldb + (k0 + s * 8);
      int ubase = (r * 256 + (tid & ~63)) * 16;  // wave-uniform byte base
      gload_lds16(ga, (char*)&As[buf][0] + ubase);
      gload_lds16(gb, (char*)&Bs[buf][0] + ubase);
    }
  };

  auto compute = [&](int buf) {
#pragma unroll
    for (int kk = 0; kk < 2; ++kk) {  // two K=32 sub-steps per BK=64 tile
      bf16x8 a[4], b[4];
#pragma unroll
      for (int i = 0; i < 4; ++i) {
        int rowa = wm * 64 + i * 16 + (lane & 15);
        int sl = kk * 4 + (lane >> 4);
        int pa = sl ^ (rowa & 7);
        a[i] = *(const bf16x8*)&As[buf][rowa * 64 + pa * 8];
        int rowb = wn * 64 + i * 16 + (lane & 15);
        int pb = sl ^ (rowb & 7);
        b[i] = *(const bf16x8*)&Bs[buf][rowb * 64 + pb * 8];
      }
#pragma unroll
      for (int mi = 0; mi < 4; ++mi)
#pragma unroll
        for (int ni = 0; ni < 4; ++ni)
          acc[mi][ni] = __builtin_amdgcn_mfma_f32_16x16x32_bf16(
              a[mi], b[ni], acc[mi][ni], 0, 0, 0);
    }
  };

  const int nk = K >> 6;
  stage(0, 0);
  __syncthreads();
  int buf = 0;
  for (int kt = 0; kt < nk - 1; ++kt) {
    stage(buf ^ 1, (kt + 1) << 6);  // issue next-tile loads first (T3 order)
    compute(buf);
    __syncthreads();  // drains vmcnt (staged tile) + orders LDS reuse
    buf ^= 1;
  }
  compute(buf);

  // epilogue: C/D map (verified m89): col = lane&15, row = (lane>>4)*4 + j
#pragma unroll
  for (int ni = 0; ni < 4; ++ni) {
    int col = n0 + wn * 64 + ni * 16 + (lane & 15);
    float bv = 0.f;
    if constexpr (HAS_BIAS) bv = bias[col];
#pragma unroll
    for (int mi = 0; mi < 4; ++mi) {
      int row0 = m0 + wm * 64 + mi * 16 + (lane >> 4) * 4;
#pragma unroll
      for (int j = 0; j < 4; ++j) {
        float o = (acc[mi][ni][j] + bv) * scale;
        size_t off = (size_t)bz * sC + (size_t)(row0 + j) * ldc + col;
        if constexpr (OUT_BF16)
          ((u16*)C)[off] = f2bf(o);
        else
          ((float*)C)[off] = o;
      }
    }
  }
}

// ---------------------------------------------------------------------------
// row softmax, fp32, in-place: reads 2048 fp32, writes 2048 bf16 into the
// first half of the same row (row byte stride stays 8192 -> PV lda = 4096).
__global__ __launch_bounds__(256) void softmax_rows(float* __restrict__ S) {
  const int t = threadIdx.x;
  const int lane = t & 63;
  const int w = t >> 6;
  float* base = S + (size_t)blockIdx.x * 2048;
  float4 v0 = ((const float4*)base)[t];
  float4 v1 = ((const float4*)base)[256 + t];
  float vals[8] = {v0.x, v0.y, v0.z, v0.w, v1.x, v1.y, v1.z, v1.w};
  float m = vals[0];
#pragma unroll
  for (int i = 1; i < 8; ++i) m = fmaxf(m, vals[i]);
#pragma unroll
  for (int off = 32; off; off >>= 1) m = fmaxf(m, __shfl_xor(m, off));
  __shared__ float red[8];
  if (lane == 0) red[w] = m;
  __syncthreads();
  m = fmaxf(fmaxf(red[0], red[1]), fmaxf(red[2], red[3]));
  float s = 0.f;
#pragma unroll
  for (int i = 0; i < 8; ++i) {
    vals[i] = __expf(vals[i] - m);
    s += vals[i];
  }
#pragma unroll
  for (int off = 32; off; off >>= 1) s += __shfl_xor(s, off);
  if (lane == 0) red[4 + w] = s;
  __syncthreads();  // reads of S are already complete; orders red[] reuse
  s = red[4] + red[5] + red[6] + red[7];
  float inv = 1.0f / s;
  ushort4 o0, o1;
  o0.x = f2bf(vals[0] * inv); o0.y = f2bf(vals[1] * inv);
  o0.z = f2bf(vals[2] * inv); o0.w = f2bf(vals[3] * inv);
  o1.x = f2bf(vals[4] * inv); o1.y = f2bf(vals[5] * inv);
  o1.z = f2bf(vals[6] * inv); o1.w = f2bf(vals[7] * inv);
  ((ushort4*)base)[t] = o0;
  ((ushort4*)base)[256 + t] = o1;
}

// ---------------------------------------------------------------------------
extern "C" void kernel_launch(void* const* d_in, const int* in_sizes, int n_in,
                              void* d_out, int out_size, void* d_ws,
                              size_t ws_size, hipStream_t stream) {
  (void)in_sizes; (void)n_in; (void)out_size; (void)ws_size;
  const float* x  = (const float*)d_in[0];
  const float* Wq = (const float*)d_in[1];
  const float* bq = (const float*)d_in[2];
  const float* Wk = (const float*)d_in[3];
  const float* bk = (const float*)d_in[4];
  const float* Wv = (const float*)d_in[5];
  const float* bv = (const float*)d_in[6];
  const float* Wo = (const float*)d_in[7];
  const float* bo = (const float*)d_in[8];

  const size_t M = (size_t)BATCH * CSEQ;  // 8192
  char* ws = (char*)d_ws;
  size_t off = 0;
  auto alloc = [&](size_t bytes) {
    char* p = ws + off;
    off += (bytes + 255) & ~(size_t)255;
    return p;
  };
  u16* x_bf = (u16*)alloc(M * DIM * 2);            // 16 MB (attn aliases later)
  u16* Wq_t = (u16*)alloc((size_t)DIM * DIM * 2);  // 2 MB each
  u16* Wk_t = (u16*)alloc((size_t)DIM * DIM * 2);
  u16* Wv_t = (u16*)alloc((size_t)DIM * DIM * 2);
  u16* Wo_t = (u16*)alloc((size_t)DIM * DIM * 2);
  u16* Qb   = (u16*)alloc(M * DIM * 2);            // 16 MB
  u16* Kb   = (u16*)alloc(M * DIM * 2);
  u16* Vb   = (u16*)alloc(M * DIM * 2);
  u16* Vt   = (u16*)alloc(M * DIM * 2);
  float* S  = (float*)alloc((size_t)BATCH * CSEQ * CSEQ * 4);  // 64 MB (S then P in-place)
  u16* attn = x_bf;  // x dead after projections; alias to save 16 MB ws

  // 1. cast x -> bf16
  int n4 = (int)(M * DIM / 4);
  cast_f32_bf16<<<n4 / 256, 256, 0, stream>>>((const float4*)x,
                                              (ushort4*)x_bf, n4);
  // 2. transpose+cast weights -> bf16 N x K
  dim3 tb(32, 8), tg(DIM / 32, DIM / 32);
  transpose_cast_w<<<tg, tb, 0, stream>>>(Wq, Wq_t, DIM, DIM);
  transpose_cast_w<<<tg, tb, 0, stream>>>(Wk, Wk_t, DIM, DIM);
  transpose_cast_w<<<tg, tb, 0, stream>>>(Wv, Wv_t, DIM, DIM);
  transpose_cast_w<<<tg, tb, 0, stream>>>(Wo, Wo_t, DIM, DIM);

  // 3. projections (Q folds the 1/sqrt(1024)=2^-5 score scale, exact in bf16)
  dim3 gproj(DIM / 128, M / 128, 1);
  gemm_bt<true, true><<<gproj, 256, 0, stream>>>(
      x_bf, Wq_t, Qb, bq, (int)M, DIM, DIM, DIM, DIM, DIM, 0, 0, 0, 0.03125f);
  gemm_bt<true, true><<<gproj, 256, 0, stream>>>(
      x_bf, Wk_t, Kb, bk, (int)M, DIM, DIM, DIM, DIM, DIM, 0, 0, 0, 1.0f);
  gemm_bt<true, true><<<gproj, 256, 0, stream>>>(
      x_bf, Wv_t, Vb, bv, (int)M, DIM, DIM, DIM, DIM, DIM, 0, 0, 0, 1.0f);

  // 4. V -> Vt[b][h][c]
  transpose_bf16<<<dim3(DIM / 32, CSEQ / 32, BATCH), tb, 0, stream>>>(
      Vb, Vt, CSEQ, DIM);

  // 5. scores S[b] = Qs[b] * K[b]^T   (K row-major IS the N x K operand)
  gemm_bt<false, false><<<dim3(CSEQ / 128, CSEQ / 128, BATCH), 256, 0, stream>>>(
      Qb, Kb, S, nullptr, CSEQ, CSEQ, DIM, DIM, DIM, CSEQ,
      (size_t)CSEQ * DIM, (size_t)CSEQ * DIM, (size_t)CSEQ * CSEQ, 1.0f);

  // 6. softmax rows, in-place S(fp32) -> P(bf16, row stride 4096 elems)
  softmax_rows<<<BATCH * CSEQ, 256, 0, stream>>>(S);

  // 7. attn[b] = P[b] * Vt[b]^T
  gemm_bt<true, false><<<dim3(DIM / 128, CSEQ / 128, BATCH), 256, 0, stream>>>(
      (const u16*)S, Vt, attn, nullptr, CSEQ, DIM, CSEQ, 2 * CSEQ, CSEQ, DIM,
      (size_t)CSEQ * 2 * CSEQ, (size_t)DIM * CSEQ, (size_t)CSEQ * DIM, 1.0f);

  // 8. out = attn * Wo + bo (fp32 out)
  gemm_bt<false, true><<<gproj, 256, 0, stream>>>(
      attn, Wo_t, d_out, bo, (int)M, DIM, DIM, DIM, DIM, DIM, 0, 0, 0, 1.0f);
}

// Round 6
// 298.764 us; speedup vs baseline: 1.0811x; 1.0811x over previous
//
#include <hip/hip_runtime.h>
#include <hip/hip_bf16.h>
#include <stdint.h>

// Self-attention: out = softmax((xWq+bq)(xWk+bk)^T / 32) (xWv+bv) Wo + bo
// B=4, C=2048, D_IN=D_H=D_OUT=1024. fp32 in/out; bf16 MFMA internally.
// R5: R4 pipeline (fused QKV, bf16 S/P) + 8-phase 256x256 kernel for scores.

typedef unsigned short u16;
typedef __attribute__((ext_vector_type(8))) short bf16x8;   // 8 bf16 = 4 VGPR
typedef __attribute__((ext_vector_type(8))) unsigned short u16x8;
typedef __attribute__((ext_vector_type(4))) float f32x4;    // MFMA 16x16 acc

#define BATCH 4
#define CSEQ  2048
#define DIM   1024
#define NQKV  3072

__device__ __forceinline__ u16 f2bf(float f) {
  union { float f; uint32_t u; } v; v.f = f;
  uint32_t r = (v.u + 0x7fffu + ((v.u >> 16) & 1u)) >> 16;  // RNE
  return (u16)r;
}
__device__ __forceinline__ float bf2f(u16 h) {
  union { uint32_t u; float f; } v; v.u = (uint32_t)h << 16;
  return v.f;
}

__device__ __forceinline__ void gload_lds16(const void* g, void* lds) {
  // async global->LDS, 16B per lane; LDS dest = wave-uniform base + lane*16
  __builtin_amdgcn_global_load_lds(
      (const __attribute__((address_space(1))) unsigned int*)g,
      (__attribute__((address_space(3))) unsigned int*)lds, 16, 0, 0);
}

// ---------------------------------------------------------------------------
__global__ __launch_bounds__(256) void cast_f32_bf16(
    const float4* __restrict__ in, ushort4* __restrict__ out, int n4) {
  int i = blockIdx.x * 256 + threadIdx.x;
  if (i < n4) {
    float4 v = in[i];
    ushort4 o;
    o.x = f2bf(v.x); o.y = f2bf(v.y); o.z = f2bf(v.z); o.w = f2bf(v.w);
    out[i] = o;
  }
}

// transpose+cast Wq/Wk/Wv (each 1024x1024) into Wt rows [z*1024, z*1024+1024);
// z=0 (Wq) folds the 1/sqrt(D_H)=2^-5 score scale (exact in bf16).
__global__ __launch_bounds__(256) void transpose_cast_qkv(
    const float* __restrict__ Wq, const float* __restrict__ Wk,
    const float* __restrict__ Wv, u16* __restrict__ Wt) {
  const int z = blockIdx.z;
  const float* W = (z == 0) ? Wq : (z == 1) ? Wk : Wv;
  const float sc = (z == 0) ? 0.03125f : 1.0f;
  __shared__ float t[32][33];
  int bx = blockIdx.x * 32, by = blockIdx.y * 32;
  int tx = threadIdx.x, ty = threadIdx.y;  // 32 x 8
#pragma unroll
  for (int i = 0; i < 4; ++i)
    t[ty + i * 8][tx] = W[(size_t)(by + ty + i * 8) * DIM + bx + tx];
  __syncthreads();
#pragma unroll
  for (int i = 0; i < 4; ++i)
    Wt[(size_t)(z * DIM + bx + ty + i * 8) * DIM + by + tx] =
        f2bf(t[tx][ty + i * 8] * sc);
}

__global__ __launch_bounds__(256) void transpose_cast_w(
    const float* __restrict__ W, u16* __restrict__ Wt, int rows, int cols) {
  __shared__ float t[32][33];
  int bx = blockIdx.x * 32, by = blockIdx.y * 32;
  int tx = threadIdx.x, ty = threadIdx.y;
#pragma unroll
  for (int i = 0; i < 4; ++i)
    t[ty + i * 8][tx] = W[(size_t)(by + ty + i * 8) * cols + bx + tx];
  __syncthreads();
#pragma unroll
  for (int i = 0; i < 4; ++i)
    Wt[(size_t)(bx + ty + i * 8) * rows + by + tx] = f2bf(t[tx][ty + i * 8]);
}

// bqkv[3072] = concat(bq * 2^-5, bk, bv)
__global__ __launch_bounds__(256) void concat_bias(
    const float* __restrict__ bq, const float* __restrict__ bk,
    const float* __restrict__ bv, float* __restrict__ bqkv) {
  int i = blockIdx.x * 256 + threadIdx.x;
  if (i < NQKV) {
    float v = (i < 1024) ? bq[i] * 0.03125f
                         : (i < 2048) ? bk[i - 1024] : bv[i - 2048];
    bqkv[i] = v;
  }
}

// generalized bf16 batch transpose: dst[z][c][r] = src[z][r][c]
__global__ __launch_bounds__(256) void transpose_bf16(
    const u16* __restrict__ src, u16* __restrict__ dst, int sld, size_t sbs,
    int dld, size_t dbs) {
  __shared__ u16 t[32][34];
  const size_t sb = (size_t)blockIdx.z * sbs;
  const size_t db = (size_t)blockIdx.z * dbs;
  int bx = blockIdx.x * 32, by = blockIdx.y * 32;
  int tx = threadIdx.x, ty = threadIdx.y;
#pragma unroll
  for (int i = 0; i < 4; ++i)
    t[ty + i * 8][tx] = src[sb + (size_t)(by + ty + i * 8) * sld + bx + tx];
  __syncthreads();
#pragma unroll
  for (int i = 0; i < 4; ++i)
    dst[db + (size_t)(bx + ty + i * 8) * dld + by + tx] = t[tx][ty + i * 8];
}

// ---------------------------------------------------------------------------
// 2-phase 128x128 GEMM (verified R3): C = A[M][K] * Bt[N][K]^T (+bias)(*scale)
template <bool OUT_BF16, bool HAS_BIAS>
__device__ __forceinline__ void gemm_body(
    const u16* __restrict__ A, const u16* __restrict__ Bt, void* __restrict__ C,
    const float* __restrict__ bias, int K, int lda, int ldb, int ldc,
    size_t sA, size_t sB, size_t sC, float scale) {
  __shared__ __align__(16) u16 As[2][128 * 64];
  __shared__ __align__(16) u16 Bs[2][128 * 64];

  const int tid = threadIdx.x;
  const int lane = tid & 63;
  const int w = tid >> 6;
  const int wm = w >> 1, wn = w & 1;
  const int bz = blockIdx.z;
  const int m0 = blockIdx.y * 128;
  const int n0 = blockIdx.x * 128;

  A += (size_t)bz * sA;
  Bt += (size_t)bz * sB;

  f32x4 acc[4][4] = {};

  auto stage = [&](int buf, int k0) {
#pragma unroll
    for (int r = 0; r < 4; ++r) {
      int flat = r * 256 + tid;
      int row = flat >> 3;
      int s = (flat & 7) ^ (row & 7);  // inverse-swizzled source (rule #21)
      const u16* ga = A + (size_t)(m0 + row) * lda + (k0 + s * 8);
      const u16* gb = Bt + (size_t)(n0 + row) * ldb + (k0 + s * 8);
      int ubase = (r * 256 + (tid & ~63)) * 16;
      gload_lds16(ga, (char*)&As[buf][0] + ubase);
      gload_lds16(gb, (char*)&Bs[buf][0] + ubase);
    }
  };

  auto compute = [&](int buf) {
#pragma unroll
    for (int kk = 0; kk < 2; ++kk) {
      bf16x8 a[4], b[4];
#pragma unroll
      for (int i = 0; i < 4; ++i) {
        int rowa = wm * 64 + i * 16 + (lane & 15);
        int sl = kk * 4 + (lane >> 4);
        a[i] = *(const bf16x8*)&As[buf][rowa * 64 + (sl ^ (rowa & 7)) * 8];
        int rowb = wn * 64 + i * 16 + (lane & 15);
        b[i] = *(const bf16x8*)&Bs[buf][rowb * 64 + (sl ^ (rowb & 7)) * 8];
      }
#pragma unroll
      for (int mi = 0; mi < 4; ++mi)
#pragma unroll
        for (int ni = 0; ni < 4; ++ni)
          acc[mi][ni] = __builtin_amdgcn_mfma_f32_16x16x32_bf16(
              a[mi], b[ni], acc[mi][ni], 0, 0, 0);
    }
  };

  const int nk = K >> 6;
  stage(0, 0);
  __syncthreads();
  int buf = 0;
  for (int kt = 0; kt < nk - 1; ++kt) {
    stage(buf ^ 1, (kt + 1) << 6);
    compute(buf);
    __syncthreads();
    buf ^= 1;
  }
  compute(buf);

#pragma unroll
  for (int ni = 0; ni < 4; ++ni) {
    int col = n0 + wn * 64 + ni * 16 + (lane & 15);
    float bv = 0.f;
    if constexpr (HAS_BIAS) bv = bias[col];
#pragma unroll
    for (int mi = 0; mi < 4; ++mi) {
      int row0 = m0 + wm * 64 + mi * 16 + (lane >> 4) * 4;
#pragma unroll
      for (int j = 0; j < 4; ++j) {
        float o = (acc[mi][ni][j] + bv) * scale;
        size_t off = (size_t)bz * sC + (size_t)(row0 + j) * ldc + col;
        if constexpr (OUT_BF16)
          ((u16*)C)[off] = f2bf(o);
        else
          ((float*)C)[off] = o;
      }
    }
  }
}

__global__ __launch_bounds__(256, 2) void gemm_qkv(
    const u16* A, const u16* Bt, void* C, const float* bias, int K, int lda,
    int ldb, int ldc, size_t sA, size_t sB, size_t sC, float scale) {
  gemm_body<true, true>(A, Bt, C, bias, K, lda, ldb, ldc, sA, sB, sC, scale);
}
__global__ __launch_bounds__(256, 2) void gemm_pv(
    const u16* A, const u16* Bt, void* C, const float* bias, int K, int lda,
    int ldb, int ldc, size_t sA, size_t sB, size_t sC, float scale) {
  gemm_body<true, false>(A, Bt, C, bias, K, lda, ldb, ldc, sA, sB, sC, scale);
}
__global__ __launch_bounds__(256, 2) void gemm_out(
    const u16* A, const u16* Bt, void* C, const float* bias, int K, int lda,
    int ldb, int ldc, size_t sA, size_t sB, size_t sC, float scale) {
  gemm_body<false, true>(A, Bt, C, bias, K, lda, ldb, ldc, sA, sB, sC, scale);
}

// ---------------------------------------------------------------------------
// 8-phase 256x256 GEMM (T2+T3+T4+T5) for scores. 512 thr = 8 waves (2M x 4N),
// BK=64, per-wave output 128x64 (8 mfrag x 4 nfrag), LDS 128 KiB:
// per buffer, per operand: 2 halves of [128][64] bf16, slot-swizzled
// (phys16Bslot = logical ^ (row&7)), linear gload_lds dest + inverse-swz src.
//
// Per K-tile: 4 phases, each {ds_reads; 1-half stage; bar; lgkm0; 16 MFMA; bar}.
// Quadrants: q0: A0-3 x B0-1 (reads 8A+4B), q1: A0-3 x B2-3 (4B),
//            q2: A4-7 x B2-3 (8A), q3: A4-7 x B0-1 (0 reads; regs held).
// Stages during tile u: q0->Bh1(u+1), q1->Ah1(u+1) (buffer 1-p, free),
//                       q2->Bh0(u+2), q3->Ah0(u+2) (own buffer p; safe: u's
//                       B-reads confirmed at q1.bar2, A-reads at q2.bar2).
// One counted vmcnt per tile at end-q3: queue=12 loads, wait 8 -> vmcnt(4);
// never 0 in steady state (T4). Epilogue drains 0 at u=nk-2.
__global__ __launch_bounds__(512, 2) void gemm_scores8(
    const u16* __restrict__ A, const u16* __restrict__ Bt, u16* __restrict__ C,
    int K, int lda, int ldb, int ldc, size_t sA, size_t sB, size_t sC) {
  __shared__ __align__(16) u16 As[2][2][128 * 64];
  __shared__ __align__(16) u16 Bs[2][2][128 * 64];

  const int tid = threadIdx.x;   // 0..511
  const int lane = tid & 63;
  const int w = tid >> 6;        // 0..7
  const int wm = w >> 2;         // 0..1  M half
  const int wn = w & 3;          // 0..3  N quarter
  const int bz = blockIdx.z;
  const int m0 = blockIdx.y * 256;
  const int n0 = blockIdx.x * 256;
  A += (size_t)bz * sA;
  Bt += (size_t)bz * sB;

  f32x4 acc[8][4] = {};

  // stage one 16KB half (128 rows x BK=64 bf16): 2 gload_lds per wave
  auto stage_half = [&](u16* ldsHalf, const u16* g, int row0, int ld, int k0) {
#pragma unroll
    for (int r = 0; r < 2; ++r) {
      int flat = r * 512 + tid;        // 16B-unit index 0..1023
      int row = flat >> 3;
      int s = (flat & 7) ^ (row & 7);  // inverse swizzle on source
      const u16* ga = g + (size_t)(row0 + row) * ld + (k0 + s * 8);
      int ubase = (r * 512 + (tid & ~63)) * 16;  // wave-uniform dest
      gload_lds16(ga, (char*)ldsHalf + ubase);
    }
  };

  const int nk = K >> 6;
  // prologue: tile0 fully + tile1's Bh0,Ah0 (order matters for vmcnt count)
  stage_half(As[0][0], A, m0, lda, 0);
  stage_half(As[0][1], A, m0 + 128, lda, 0);
  stage_half(Bs[0][0], Bt, n0, ldb, 0);
  stage_half(Bs[0][1], Bt, n0 + 128, ldb, 0);
  stage_half(Bs[1][0], Bt, n0, ldb, 64);
  stage_half(As[1][0], A, m0, lda, 64);
  asm volatile("s_waitcnt vmcnt(4)" ::: "memory");  // tile0 in; 4 in flight
  asm volatile("s_barrier" ::: "memory");

  for (int t = 0; t < nk; ++t) {
    const int p = t & 1;
    const u16* Abuf = &As[p][wm][0];
    const u16* Bbuf = &Bs[p][wn >> 1][0];
    const int bR0 = (wn & 1) * 64;  // B row base within half
    const int rl = lane & 15;
    const int su = lane >> 4;       // slot sub-index
    bf16x8 a[4][2], b[4][2];

    auto rdA = [&](int fi, int fbase) {
#pragma unroll
      for (int ks = 0; ks < 2; ++ks) {
        int row = (fbase + fi) * 16 + rl;
        int sl = ks * 4 + su;
        a[fi][ks] = *(const bf16x8*)&Abuf[row * 64 + ((sl ^ (row & 7))) * 8];
      }
    };
    auto rdB = [&](int nf) {
#pragma unroll
      for (int ks = 0; ks < 2; ++ks) {
        int row = bR0 + nf * 16 + rl;
        int sl = ks * 4 + su;
        b[nf][ks] = *(const bf16x8*)&Bbuf[row * 64 + ((sl ^ (row & 7))) * 8];
      }
    };
    auto quad = [&](int mbase, int nbase) {
      __builtin_amdgcn_s_setprio(1);
#pragma unroll
      for (int fi = 0; fi < 4; ++fi)
#pragma unroll
        for (int nf = 0; nf < 2; ++nf)
#pragma unroll
          for (int ks = 0; ks < 2; ++ks)
            acc[mbase + fi][nbase + nf] = __builtin_amdgcn_mfma_f32_16x16x32_bf16(
                a[fi][ks], b[nbase + nf][ks], acc[mbase + fi][nbase + nf], 0, 0, 0);
      __builtin_amdgcn_s_setprio(0);
    };
    auto barrier_in = [&]() {
      asm volatile("s_barrier" ::: "memory");
      asm volatile("s_waitcnt lgkmcnt(0)" ::: "memory");
      __builtin_amdgcn_sched_barrier(0);  // rule #18: pin MFMA after the wait
    };

    // ---- phase 0: A0-3, B0-1 -> quad(0,0); stage Bh1(t+1)
    rdA(0, 0); rdA(1, 0); rdA(2, 0); rdA(3, 0);
    rdB(0); rdB(1);
    if (t + 1 < nk) stage_half(Bs[1 - p][1], Bt, n0 + 128, ldb, (t + 1) * 64);
    barrier_in();
    quad(0, 0);
    asm volatile("s_barrier" ::: "memory");

    // ---- phase 1: B2-3 -> quad(0,2); stage Ah1(t+1)
    rdB(2); rdB(3);
    if (t + 1 < nk) stage_half(As[1 - p][1], A, m0 + 128, lda, (t + 1) * 64);
    barrier_in();
    quad(0, 2);
    asm volatile("s_barrier" ::: "memory");

    // ---- phase 2: A4-7 -> quad(4,2); stage Bh0(t+2) into own buffer
    rdA(0, 4); rdA(1, 4); rdA(2, 4); rdA(3, 4);
    if (t + 2 < nk) stage_half(Bs[p][0], Bt, n0, ldb, (t + 2) * 64);
    barrier_in();
    quad(4, 2);
    asm volatile("s_barrier" ::: "memory");

    // ---- phase 3: no reads -> quad(4,0); stage Ah0(t+2); tile-boundary wait
    if (t + 2 < nk) stage_half(As[p][0], A, m0, lda, (t + 2) * 64);
    barrier_in();  // (no lgkm work pending; keeps phase lockstep)
    quad(4, 0);
    if (t + 2 < nk)
      asm volatile("s_waitcnt vmcnt(4)" ::: "memory");  // t+1 landed, 4 fly
    else if (t + 1 < nk)
      asm volatile("s_waitcnt vmcnt(0)" ::: "memory");  // epilogue drain
    asm volatile("s_barrier" ::: "memory");
  }

  const size_t cb = (size_t)bz * sC;
#pragma unroll
  for (int fi = 0; fi < 8; ++fi) {
    int row0 = m0 + wm * 128 + fi * 16 + (lane >> 4) * 4;
#pragma unroll
    for (int nf = 0; nf < 4; ++nf) {
      int col = n0 + wn * 64 + nf * 16 + (lane & 15);
#pragma unroll
      for (int j = 0; j < 4; ++j)
        C[cb + (size_t)(row0 + j) * ldc + col] = f2bf(acc[fi][nf][j]);
    }
  }
}

// ---------------------------------------------------------------------------
// row softmax over bf16 S, fp32 math, in-place (one block per row, 2048 cols)
__global__ __launch_bounds__(256) void softmax_bf16(u16* __restrict__ S) {
  const int t = threadIdx.x;
  const int lane = t & 63;
  const int w = t >> 6;
  u16* base = S + (size_t)blockIdx.x * 2048;
  u16x8 v = *(const u16x8*)(base + t * 8);
  float vals[8];
#pragma unroll
  for (int i = 0; i < 8; ++i) vals[i] = bf2f(v[i]);
  float m = vals[0];
#pragma unroll
  for (int i = 1; i < 8; ++i) m = fmaxf(m, vals[i]);
#pragma unroll
  for (int off = 32; off; off >>= 1) m = fmaxf(m, __shfl_xor(m, off));
  __shared__ float red[8];
  if (lane == 0) red[w] = m;
  __syncthreads();
  m = fmaxf(fmaxf(red[0], red[1]), fmaxf(red[2], red[3]));
  float s = 0.f;
#pragma unroll
  for (int i = 0; i < 8; ++i) {
    vals[i] = __expf(vals[i] - m);
    s += vals[i];
  }
#pragma unroll
  for (int off = 32; off; off >>= 1) s += __shfl_xor(s, off);
  if (lane == 0) red[4 + w] = s;
  __syncthreads();
  s = red[4] + red[5] + red[6] + red[7];
  float inv = 1.0f / s;
  u16x8 o;
#pragma unroll
  for (int i = 0; i < 8; ++i) o[i] = f2bf(vals[i] * inv);
  *(u16x8*)(base + t * 8) = o;
}

// ---------------------------------------------------------------------------
extern "C" void kernel_launch(void* const* d_in, const int* in_sizes, int n_in,
                              void* d_out, int out_size, void* d_ws,
                              size_t ws_size, hipStream_t stream) {
  (void)in_sizes; (void)n_in; (void)out_size; (void)ws_size;
  const float* x  = (const float*)d_in[0];
  const float* Wq = (const float*)d_in[1];
  const float* bq = (const float*)d_in[2];
  const float* Wk = (const float*)d_in[3];
  const float* bk = (const float*)d_in[4];
  const float* Wv = (const float*)d_in[5];
  const float* bv = (const float*)d_in[6];
  const float* Wo = (const float*)d_in[7];
  const float* bo = (const float*)d_in[8];

  const size_t M = (size_t)BATCH * CSEQ;  // 8192
  char* ws = (char*)d_ws;
  size_t off = 0;
  auto alloc = [&](size_t bytes) {
    char* p = ws + off;
    off += (bytes + 255) & ~(size_t)255;
    return p;
  };
  u16* x_bf   = (u16*)alloc(M * DIM * 2);             // 16 MB (attn aliases)
  u16* Wqkv_t = (u16*)alloc((size_t)NQKV * DIM * 2);  // 6 MB
  u16* Wo_t   = (u16*)alloc((size_t)DIM * DIM * 2);   // 2 MB
  float* bqkv = (float*)alloc(NQKV * 4);              // 12 KB
  u16* QKV    = (u16*)alloc(M * NQKV * 2);            // 48 MB
  u16* Vt     = (u16*)alloc(M * DIM * 2);             // 16 MB
  u16* S      = (u16*)alloc((size_t)BATCH * CSEQ * CSEQ * 2);  // 32 MB
  u16* attn   = x_bf;  // x dead after QKV GEMM

  // 1. cast x -> bf16
  int n4 = (int)(M * DIM / 4);
  cast_f32_bf16<<<n4 / 256, 256, 0, stream>>>((const float4*)x,
                                              (ushort4*)x_bf, n4);
  // 2. weights -> bf16 N x K (Q pre-scaled by 2^-5), bias concat
  dim3 tb(32, 8);
  transpose_cast_qkv<<<dim3(32, 32, 3), tb, 0, stream>>>(Wq, Wk, Wv, Wqkv_t);
  transpose_cast_w<<<dim3(32, 32), tb, 0, stream>>>(Wo, Wo_t, DIM, DIM);
  concat_bias<<<(NQKV + 255) / 256, 256, 0, stream>>>(bq, bk, bv, bqkv);

  // 3. fused QKV projection: QKV[8192][3072] = x_bf * Wqkv_t^T + bqkv
  gemm_qkv<<<dim3(NQKV / 128, M / 128, 1), 256, 0, stream>>>(
      x_bf, Wqkv_t, QKV, bqkv, DIM, DIM, DIM, NQKV, 0, 0, 0, 1.0f);

  // 4. V (cols 2048..3071 of QKV) -> Vt[b][h][c]
  transpose_bf16<<<dim3(DIM / 32, CSEQ / 32, BATCH), tb, 0, stream>>>(
      QKV + 2048, Vt, NQKV, (size_t)CSEQ * NQKV, CSEQ, (size_t)DIM * CSEQ);

  // 5. scores S[b] = Qs[b] * K[b]^T  (8-phase 256^2; grid = 256 blocks = 1/CU)
  gemm_scores8<<<dim3(CSEQ / 256, CSEQ / 256, BATCH), 512, 0, stream>>>(
      QKV, QKV + 1024, S, DIM, NQKV, NQKV, CSEQ,
      (size_t)CSEQ * NQKV, (size_t)CSEQ * NQKV, (size_t)CSEQ * CSEQ);

  // 6. softmax rows, fp32 math, bf16 in-place
  softmax_bf16<<<BATCH * CSEQ, 256, 0, stream>>>(S);

  // 7. attn[b] = P[b] * Vt[b]^T
  gemm_pv<<<dim3(DIM / 128, CSEQ / 128, BATCH), 256, 0, stream>>>(
      S, Vt, attn, nullptr, CSEQ, CSEQ, CSEQ, DIM, (size_t)CSEQ * CSEQ,
      (size_t)DIM * CSEQ, (size_t)CSEQ * DIM, 1.0f);

  // 8. out = attn * Wo_t^T + bo (fp32 out)
  gemm_out<<<dim3(DIM / 128, M / 128, 1), 256, 0, stream>>>(
      attn, Wo_t, d_out, bo, DIM, DIM, DIM, DIM, 0, 0, 0, 1.0f);
}